// Round 7
// baseline (221.864 us; speedup 1.0000x reference)
//
#include <hip/hip_runtime.h>
#include <math.h>

// ---------------- problem constants ----------------
#define CIN   512
#define NOUT  123      // DEPTH + CT
#define OP    128      // padded row
#define DEPN  59
#define CT    64
#define B_    4
#define N_    6
#define FH    16
#define FW    44
#define HW    704      // FH*FW
#define NPIX  (B_*N_*HW)          // 16896
#define NX    128
#define BEV_ELEMS (B_*CT*NX*NX)   // 4,194,304
#define DEPTH_OFF BEV_ELEMS

// ws layout (float offsets). Double region first (8B aligned at base).
#define TDREC   40
#define WS_WT   1920                       // transposed weight [512][128]
#define WS_OUT  (WS_WT + CIN*OP)           // [16896][128] conv output
#define WS_PS   (WS_OUT + NPIX*OP)         // p-slab [bw][59][96]
#define WS_C    (WS_PS + B_*FW*DEPN*96)    // group sums [bw][59][64]
#define WS_VOX  (WS_C + B_*FW*DEPN*64)     // int [bw][59]

// ---------------- K0: weight transpose + per-(b,n) f64 transforms ----------------
__device__ inline void inv3d(const double* m, double* o) {
    #pragma clang fp contract(off)
    double c00 = m[4]*m[8] - m[5]*m[7];
    double c01 = m[5]*m[6] - m[3]*m[8];
    double c02 = m[3]*m[7] - m[4]*m[6];
    double det = m[0]*c00 + m[1]*c01 + m[2]*c02;
    o[0] = c00/det; o[1] = (m[2]*m[7]-m[1]*m[8])/det; o[2] = (m[1]*m[5]-m[2]*m[4])/det;
    o[3] = c01/det; o[4] = (m[0]*m[8]-m[2]*m[6])/det; o[5] = (m[2]*m[3]-m[0]*m[5])/det;
    o[6] = c02/det; o[7] = (m[1]*m[6]-m[0]*m[7])/det; o[8] = (m[0]*m[4]-m[1]*m[3])/det;
}
__device__ inline void mm3d(const double* a, const double* b, double* o) {
    #pragma clang fp contract(off)
    for (int i = 0; i < 3; ++i)
        for (int k = 0; k < 3; ++k)
            o[i*3+k] = (a[i*3+0]*b[0*3+k] + a[i*3+1]*b[1*3+k]) + a[i*3+2]*b[2*3+k];
}

__global__ void k0_prep(const float* __restrict__ rots, const float* __restrict__ trans,
                        const float* __restrict__ intr, const float* __restrict__ prots,
                        const float* __restrict__ ptrans, const float* __restrict__ bda,
                        const float* __restrict__ W, float* __restrict__ ws) {
    int tid = blockIdx.x * 256 + threadIdx.x;
    int stride = gridDim.x * 256;
    for (int i = tid; i < CIN * OP; i += stride) {
        int c = i >> 7, o = i & 127;
        ws[WS_WT + i] = (o < NOUT) ? W[o * CIN + c] : 0.0f;
    }
    if (blockIdx.x == 0 && threadIdx.x < B_ * N_) {
        #pragma clang fp contract(off)
        int t = threadIdx.x;
        int b = t / N_;
        double* X = (double*)(ws) + t * TDREC;
        double PR[9], Kd[9], Rd[9], Bd[9];
        for (int i = 0; i < 9; ++i) PR[i] = (double)prots[t * 9 + i];
        for (int i = 0; i < 9; ++i) Kd[i] = (double)intr[t * 9 + i];
        for (int i = 0; i < 9; ++i) Rd[i] = (double)rots[t * 9 + i];
        for (int i = 0; i < 9; ++i) Bd[i] = (double)bda[b * 9 + i];
        double iPR[9]; inv3d(PR, iPR);
        for (int i = 0; i < 9; ++i) X[i] = iPR[i];
        for (int i = 0; i < 3; ++i) X[9 + i] = (double)ptrans[t * 3 + i];
        double iK[9];  inv3d(Kd, iK);
        double comb[9]; mm3d(Rd, iK, comb);
        for (int i = 0; i < 9; ++i) X[12 + i] = comb[i];
        for (int i = 0; i < 3; ++i) X[21 + i] = (double)trans[t * 3 + i];
        for (int i = 0; i < 9; ++i) X[24 + i] = Bd[i];
    }
}

// ---------------- K1: 1x1 conv GEMM, in-block split-K ----------------
// 512 threads = two 256-thread K-groups, each with private LDS buffers.
// 8 waves/block x 2 blocks/CU = 16 waves/CU (2x the round-6 occupancy).
__global__ __launch_bounds__(512) void k1_gemm(const float* __restrict__ x,
                                               const float* __restrict__ bias,
                                               float* __restrict__ ws) {
    __shared__ float sx[2][32][32];    // [kgrp][c][pix]
    __shared__ float sw[2][32][128];   // [kgrp][c][o]
    __shared__ float sred[256][16];    // cross-group reduction
    const int tid = threadIdx.x;
    const int g = tid >> 8;            // K-split group (wave-aligned)
    const int t = tid & 255;
    const int og4 = (t & 31) * 4;
    const int pg4 = (t >> 5) * 4;
    const int bn = blockIdx.y;
    const int hwbase = blockIdx.x * 32;
    const float* xg = x + (size_t)bn * CIN * HW + hwbase;
    const float* wT = ws + WS_WT;
    float acc[4][4] = {};
    for (int ck0 = 0; ck0 < CIN; ck0 += 64) {
        const int ck = ck0 + g * 32;
        __syncthreads();
        {
            int r = t >> 3, c4 = (t & 7) * 4;
            *(float4*)&sx[g][r][c4] = *(const float4*)(xg + (size_t)(ck + r) * HW + c4);
        }
        {
            int o4 = (t & 31) * 4, rb = t >> 5;
            #pragma unroll
            for (int rr = 0; rr < 4; ++rr) {
                int r = rb + rr * 8;
                *(float4*)&sw[g][r][o4] = *(const float4*)(wT + (size_t)(ck + r) * OP + o4);
            }
        }
        __syncthreads();
        #pragma unroll
        for (int cc = 0; cc < 32; ++cc) {
            const float4 wv = *(const float4*)&sw[g][cc][og4];
            const float4 xv = *(const float4*)&sx[g][cc][pg4];
            acc[0][0] = fmaf(xv.x, wv.x, acc[0][0]); acc[0][1] = fmaf(xv.x, wv.y, acc[0][1]);
            acc[0][2] = fmaf(xv.x, wv.z, acc[0][2]); acc[0][3] = fmaf(xv.x, wv.w, acc[0][3]);
            acc[1][0] = fmaf(xv.y, wv.x, acc[1][0]); acc[1][1] = fmaf(xv.y, wv.y, acc[1][1]);
            acc[1][2] = fmaf(xv.y, wv.z, acc[1][2]); acc[1][3] = fmaf(xv.y, wv.w, acc[1][3]);
            acc[2][0] = fmaf(xv.z, wv.x, acc[2][0]); acc[2][1] = fmaf(xv.z, wv.y, acc[2][1]);
            acc[2][2] = fmaf(xv.z, wv.z, acc[2][2]); acc[2][3] = fmaf(xv.z, wv.w, acc[2][3]);
            acc[3][0] = fmaf(xv.w, wv.x, acc[3][0]); acc[3][1] = fmaf(xv.w, wv.y, acc[3][1]);
            acc[3][2] = fmaf(xv.w, wv.z, acc[3][2]); acc[3][3] = fmaf(xv.w, wv.w, acc[3][3]);
        }
    }
    __syncthreads();
    if (g == 1) {
        #pragma unroll
        for (int i = 0; i < 4; ++i)
            #pragma unroll
            for (int j = 0; j < 4; ++j) sred[t][i * 4 + j] = acc[i][j];
    }
    __syncthreads();
    if (g == 0) {
        float bb[4];
        #pragma unroll
        for (int j = 0; j < 4; ++j) bb[j] = (og4 + j < NOUT) ? bias[og4 + j] : 0.0f;
        float* out = ws + WS_OUT;
        #pragma unroll
        for (int i = 0; i < 4; ++i) {
            size_t pix = (size_t)bn * HW + hwbase + pg4 + i;
            float4 st = { acc[i][0] + sred[t][i*4+0] + bb[0], acc[i][1] + sred[t][i*4+1] + bb[1],
                          acc[i][2] + sred[t][i*4+2] + bb[2], acc[i][3] + sred[t][i*4+3] + bb[3] };
            *(float4*)(out + pix * OP + og4) = st;
        }
    }
}

// ---------------- K2b: fused softmax + geometry + group-GEMM, depth-split ----------
// Grid (B*FW, 4): blockIdx.y covers ~15 depth bins -> 704 blocks (2.75/CU).
#define DQ 15
__global__ __launch_bounds__(256) void k2b_fused(float* __restrict__ ws,
                                                 float* __restrict__ dout) {
    __shared__ float sRow[96][124];            // conv rows -> p (0..58) + feats (59..122)
    __shared__ unsigned short sv16[DQ * 96];   // per-(dlocal,j) voxel id or 0xFFFF
    __shared__ double sT[N_ * TDREC];
    __shared__ int sflag[DQ];
    const int tid = threadIdx.x;
    const int bw = blockIdx.x;
    const int b = bw / FW, w = bw - b * FW;
    const int dbase = blockIdx.y * DQ;
    const int nd = min(DQ, DEPN - dbase);

    // A: stage conv rows + transforms
    {
        const float* outbase = ws + WS_OUT;
        for (int i = tid; i < 96 * 31; i += 256) {
            int r = i / 31, c4 = (i - r * 31) * 4;
            int n = r >> 4, h = r & 15;
            size_t pix = (size_t)(b * N_ + n) * HW + (size_t)h * FW + w;
            *(float4*)&sRow[r][c4] = *(const float4*)(outbase + pix * OP + c4);
        }
        if (tid < N_ * TDREC) sT[tid] = ((const double*)ws)[b * (N_ * TDREC) + tid];
    }
    __syncthreads();

    // B: softmax per row (needs full 59-col row; one wave handles 24 rows)
    {
        const int lane = tid & 63;
        for (int r = (tid >> 6) * 24; r < (tid >> 6) * 24 + 24; ++r) {
            float v = (lane < DEPN) ? sRow[r][lane] : -INFINITY;
            float m = v;
            #pragma unroll
            for (int off = 32; off > 0; off >>= 1) m = fmaxf(m, __shfl_xor(m, off, 64));
            float e = (lane < DEPN) ? expf(v - m) : 0.0f;
            float s = e;
            #pragma unroll
            for (int off = 32; off > 0; off >>= 1) s += __shfl_xor(s, off, 64);
            if (lane < DEPN) sRow[r][lane] = e / s;
        }
    }
    __syncthreads();

    // C: dump this block's p-slab range [dbase..dbase+nd) to ws (coalesced)
    {
        float* ps = ws + WS_PS + (size_t)bw * (DEPN * 96);
        for (int idx = tid; idx < nd * 96; idx += 256) {
            int dl = idx / 96, j = idx - dl * 96;
            ps[(dbase + dl) * 96 + j] = sRow[j][dbase + dl];
        }
    }
    // D: geometry for this d-range. Bit-exact validated f64 chain.
    {
        #pragma clang fp contract(off)
        const double xs = (w == 43) ? 703.0 : (double)w * (703.0 / 43.0);
        const double BXY = (double)(-51.2000007629394531f);  // f32 value of BX-DX/2
        for (int idx = tid; idx < nd * 96; idx += 256) {
            int dl = idx / 96, j = idx - dl * 96;
            int n = j >> 4, h = j & 15;
            const double* T = &sT[n * TDREC];
            const double ys = (double)(h * 17);
            const double u0 = xs - T[9];
            const double u1 = ys - T[10];
            const double u2 = (double)(dbase + dl + 1) - T[11];
            const double p0 = (T[0]*u0 + T[1]*u1) + T[2]*u2;
            const double p1 = (T[3]*u0 + T[4]*u1) + T[5]*u2;
            const double p2 = (T[6]*u0 + T[7]*u1) + T[8]*u2;
            const double q0 = p0 * p2, q1 = p1 * p2, q2 = p2;
            const double r0 = ((T[12]*q0 + T[13]*q1) + T[14]*q2) + T[21];
            const double r1 = ((T[15]*q0 + T[16]*q1) + T[17]*q2) + T[22];
            const double r2 = ((T[18]*q0 + T[19]*q1) + T[20]*q2) + T[23];
            const double g0 = (T[24]*r0 + T[25]*r1) + T[26]*r2;
            const double g1 = (T[27]*r0 + T[28]*r1) + T[29]*r2;
            const double g2 = (T[30]*r0 + T[31]*r1) + T[32]*r2;
            const double fx = floor((g0 - BXY) / 0.8);
            const double fy = floor((g1 - BXY) / 0.8);
            const bool keep = (fx >= 0.0) & (fx < 128.0) & (fy >= 0.0) & (fy < 128.0) &
                              (g2 >= -10.0) & (g2 < 10.0);
            sv16[idx] = keep ? (unsigned short)((int)fx * NX + (int)fy) : (unsigned short)0xFFFF;
        }
    }
    __syncthreads();

    // E: per-d uniformity flags + mask dropped p's to zero
    if (tid < nd) {
        int u = -1; bool mix = false;
        for (int j = 0; j < 96; ++j) {
            int v = sv16[tid * 96 + j];
            if (v != 0xFFFF) { if (u < 0) u = v; else if (v != u) mix = true; }
        }
        sflag[tid] = mix ? -2 : u;
        ((int*)(ws + WS_VOX))[bw * DEPN + dbase + tid] = mix ? -1 : u;
    }
    for (int idx = tid; idx < nd * 96; idx += 256) {
        if (sv16[idx] == 0xFFFF) {
            int dl = idx / 96, j = idx - dl * 96;
            sRow[j][dbase + dl] = 0.0f;
        }
    }
    __syncthreads();

    // F: C[d][c] = sum_j p[j][d] * f[j][c]; thread = (d_local, 4 channels)
    const int di = tid >> 4, ci = tid & 15;
    if (di < nd) {
        float a0 = 0.f, a1 = 0.f, a2 = 0.f, a3 = 0.f;
        const int dcol = dbase + di;
        for (int j = 0; j < 96; ++j) {
            const float p = sRow[j][dcol];
            const float4 f4 = *(const float4*)&sRow[j][DEPN + 4 * ci];
            a0 = fmaf(p, f4.x, a0); a1 = fmaf(p, f4.y, a1);
            a2 = fmaf(p, f4.z, a2); a3 = fmaf(p, f4.w, a3);
        }
        float* cg = ws + WS_C + (size_t)bw * (DEPN * 64);
        float4 st = { a0, a1, a2, a3 };
        *(float4*)&cg[dcol * 64 + 4 * ci] = st;
    }
    // G: rare per-point slow path for mixed groups
    for (int dl = 0; dl < nd; ++dl) {
        if (sflag[dl] == -2) {
            int c = tid & 63, g = tid >> 6;
            for (int jj = 0; jj < 24; ++jj) {
                int j = g * 24 + jj;
                int v = sv16[dl * 96 + j];
                if (v != 0xFFFF)
                    atomicAdd(dout + (((size_t)(b * CT + c)) << 14) + v,
                              sRow[j][dbase + dl] * sRow[j][DEPN + c]);
            }
        }
    }
}

// ---------------- K2c: per-(b,d) voxel reduction + depth output (k2d merged) -------
__global__ __launch_bounds__(256) void k2c_reduce(const float* __restrict__ ws,
                                                  float* __restrict__ dout) {
    __shared__ float acc[FW][64];
    __shared__ int tags[FW];
    __shared__ unsigned char slot[FW];
    __shared__ int wvox[FW];
    __shared__ int nsh;
    const int d = blockIdx.x, b = blockIdx.y;
    const int tid = threadIdx.x;
    if (tid < FW) wvox[tid] = ((const int*)(ws + WS_VOX))[(b * FW + tid) * DEPN + d];
    for (int i = tid; i < FW * 64; i += 256) (&acc[0][0])[i] = 0.0f;
    __syncthreads();
    if (tid < 64) {  // wave 0: dedup voxel ids into slots
        const int lane = tid;
        int v = (lane < FW) ? wvox[lane] : -1;
        int firstw = lane;
        for (int w2 = 0; w2 < FW; ++w2) {
            int vw = __shfl(v, w2, 64);
            if (v >= 0 && vw == v && w2 < firstw) firstw = w2;
        }
        unsigned long long leaders = __ballot(v >= 0 && firstw == lane);
        if (lane < FW) {
            if (v >= 0) {
                int s = __popcll(leaders & ((1ull << firstw) - 1ull));
                slot[lane] = (unsigned char)s;
                if (firstw == lane) tags[s] = v;
            } else slot[lane] = 255;
        }
        if (lane == 0) nsh = __popcll(leaders);
    }
    __syncthreads();
    const int c = tid & 63, g = tid >> 6;
    for (int w = g; w < FW; w += 4) {
        if (wvox[w] >= 0) {
            float v = ws[WS_C + ((size_t)(b * FW + w) * DEPN + d) * 64 + c];
            atomicAdd(&acc[slot[w]][c], v);
        }
    }
    __syncthreads();
    const int ns = nsh;
    for (int s = g; s < ns; s += 4)
        atomicAdd(dout + (((size_t)(b * CT + c)) << 14) + tags[s], acc[s][c]);
    // depth output for this (b,d): all n, coalesced writes (L1 reuses p-slab lines)
    for (int i = tid; i < N_ * HW; i += 256) {
        int n = i / HW, t2 = i - n * HW;
        int h = t2 / FW, w2 = t2 - h * FW;
        float p = ws[WS_PS + ((size_t)(b * FW + w2) * DEPN + d) * 96 + n * FH + h];
        dout[DEPTH_OFF + ((size_t)(b * N_ + n) * DEPN + d) * HW + t2] = p;
    }
}

// ---------------- launcher ----------------
extern "C" void kernel_launch(void* const* d_in, const int* in_sizes, int n_in,
                              void* d_out, int out_size, void* d_ws, size_t ws_size,
                              hipStream_t stream) {
    const float* x      = (const float*)d_in[0];
    const float* rots   = (const float*)d_in[1];
    const float* trans  = (const float*)d_in[2];
    const float* intr   = (const float*)d_in[3];
    const float* prots  = (const float*)d_in[4];
    const float* ptrans = (const float*)d_in[5];
    const float* bda    = (const float*)d_in[6];
    const float* W      = (const float*)d_in[7];
    const float* bias   = (const float*)d_in[8];
    float* out = (float*)d_out;
    float* ws  = (float*)d_ws;

    hipMemsetAsync(d_out, 0, (size_t)BEV_ELEMS * sizeof(float), stream);
    k0_prep<<<128, 256, 0, stream>>>(rots, trans, intr, prots, ptrans, bda, W, ws);
    k1_gemm<<<dim3(HW / 32, B_ * N_), 512, 0, stream>>>(x, bias, ws);
    k2b_fused<<<dim3(B_ * FW, 4), 256, 0, stream>>>(ws, out);
    k2c_reduce<<<dim3(DEPN, B_), 256, 0, stream>>>(ws, out);
}

// Round 8
// 202.225 us; speedup vs baseline: 1.0971x; 1.0971x over previous
//
#include <hip/hip_runtime.h>
#include <math.h>

// ---------------- problem constants ----------------
#define CIN   512
#define NOUT  123      // DEPTH + CT
#define OP    128      // padded row
#define DEPN  59
#define CT    64
#define B_    4
#define N_    6
#define FH    16
#define FW    44
#define HW    704      // FH*FW
#define NPIX  (B_*N_*HW)          // 16896
#define NX    128
#define BEV_ELEMS (B_*CT*NX*NX)   // 4,194,304
#define DEPTH_OFF BEV_ELEMS

// ws layout (float offsets). Double region first (8B aligned at base).
#define TDREC   40
#define WS_WB   1920                       // bf16 weight [128 o][512 c] (zero-padded o>=123)
#define WS_OUT  (WS_WB + 32768)            // [16896][128] conv output f32
#define WS_PS   (WS_OUT + NPIX*OP)         // p-slab [bw][59][96]
#define WS_C    (WS_PS + B_*FW*DEPN*96)    // group sums [bw][59][64]
#define WS_VOX  (WS_C + B_*FW*DEPN*64)     // int [bw][59]

typedef short bf16x8 __attribute__((ext_vector_type(8)));
typedef float f32x4  __attribute__((ext_vector_type(4)));

__device__ inline unsigned short f2bf(float f) {   // RNE f32->bf16
    unsigned u = __float_as_uint(f);
    return (unsigned short)((u + 0x7fffu + ((u >> 16) & 1u)) >> 16);
}

// ---------------- K0: bf16 weight build + per-(b,n) f64 transforms ----------------
__device__ inline void inv3d(const double* m, double* o) {
    #pragma clang fp contract(off)
    double c00 = m[4]*m[8] - m[5]*m[7];
    double c01 = m[5]*m[6] - m[3]*m[8];
    double c02 = m[3]*m[7] - m[4]*m[6];
    double det = m[0]*c00 + m[1]*c01 + m[2]*c02;
    o[0] = c00/det; o[1] = (m[2]*m[7]-m[1]*m[8])/det; o[2] = (m[1]*m[5]-m[2]*m[4])/det;
    o[3] = c01/det; o[4] = (m[0]*m[8]-m[2]*m[6])/det; o[5] = (m[2]*m[3]-m[0]*m[5])/det;
    o[6] = c02/det; o[7] = (m[1]*m[6]-m[0]*m[7])/det; o[8] = (m[0]*m[4]-m[1]*m[3])/det;
}
__device__ inline void mm3d(const double* a, const double* b, double* o) {
    #pragma clang fp contract(off)
    for (int i = 0; i < 3; ++i)
        for (int k = 0; k < 3; ++k)
            o[i*3+k] = (a[i*3+0]*b[0*3+k] + a[i*3+1]*b[1*3+k]) + a[i*3+2]*b[2*3+k];
}

__global__ void k0_prep(const float* __restrict__ rots, const float* __restrict__ trans,
                        const float* __restrict__ intr, const float* __restrict__ prots,
                        const float* __restrict__ ptrans, const float* __restrict__ bda,
                        const float* __restrict__ W, float* __restrict__ ws) {
    int tid = blockIdx.x * 256 + threadIdx.x;
    int stride = gridDim.x * 256;
    unsigned short* wb = (unsigned short*)(ws + WS_WB);
    for (int i = tid; i < 128 * CIN; i += stride) {
        int o = i >> 9, c = i & 511;
        wb[i] = (o < NOUT) ? f2bf(W[o * CIN + c]) : (unsigned short)0;
    }
    if (blockIdx.x == 0 && threadIdx.x < B_ * N_) {
        #pragma clang fp contract(off)
        int t = threadIdx.x;
        int b = t / N_;
        double* X = (double*)(ws) + t * TDREC;
        double PR[9], Kd[9], Rd[9], Bd[9];
        for (int i = 0; i < 9; ++i) PR[i] = (double)prots[t * 9 + i];
        for (int i = 0; i < 9; ++i) Kd[i] = (double)intr[t * 9 + i];
        for (int i = 0; i < 9; ++i) Rd[i] = (double)rots[t * 9 + i];
        for (int i = 0; i < 9; ++i) Bd[i] = (double)bda[b * 9 + i];
        double iPR[9]; inv3d(PR, iPR);
        for (int i = 0; i < 9; ++i) X[i] = iPR[i];
        for (int i = 0; i < 3; ++i) X[9 + i] = (double)ptrans[t * 3 + i];
        double iK[9];  inv3d(Kd, iK);
        double comb[9]; mm3d(Rd, iK, comb);
        for (int i = 0; i < 9; ++i) X[12 + i] = comb[i];
        for (int i = 0; i < 3; ++i) X[21 + i] = (double)trans[t * 3 + i];
        for (int i = 0; i < 9; ++i) X[24 + i] = Bd[i];
    }
}

// ---------------- K1: bf16 MFMA GEMM  out[pix][o] = x[c][pix] @ W[o][c] + bias ----
// Block: 64 pix x 128 o, 4 waves (16 pix each). K-chunks of 64, A staged f32->bf16
// transposed in LDS (stride 72 u16 = 144 B, 16B-aligned rows), B from global wB.
__global__ __launch_bounds__(256) void k1_gemm(const float* __restrict__ x,
                                               const float* __restrict__ bias,
                                               float* __restrict__ ws) {
    __shared__ unsigned short sxa[64][72];   // A tile bf16 [pix][c]
    const int tid = threadIdx.x;
    const int wave = tid >> 6, lane = tid & 63;
    const int l15 = lane & 15, quad = lane >> 4;
    const int bn = blockIdx.y;
    const int pixbase = blockIdx.x * 64;
    const float* xg = x + (size_t)bn * CIN * HW + pixbase;
    const unsigned short* wb = (const unsigned short*)(ws + WS_WB);

    // staging assignment: cpack = tid>>4 (4 c's), pix4 = (tid&15)*4
    const int cpack = tid >> 4;
    const int pix4 = (tid & 15) * 4;

    f32x4 acc[8] = {};
    for (int ck = 0; ck < CIN; ck += 64) {
        __syncthreads();
        {   // stage 64c x 64pix, transpose+convert
            const float* src = xg + (size_t)(ck + 4 * cpack) * HW + pix4;
            const float4 r0 = *(const float4*)(src);
            const float4 r1 = *(const float4*)(src + HW);
            const float4 r2 = *(const float4*)(src + 2 * HW);
            const float4 r3 = *(const float4*)(src + 3 * HW);
            const float* f0 = (const float*)&r0; const float* f1 = (const float*)&r1;
            const float* f2 = (const float*)&r2; const float* f3 = (const float*)&r3;
            #pragma unroll
            for (int i = 0; i < 4; ++i) {
                uint2 pk;
                pk.x = (unsigned)f2bf(f0[i]) | ((unsigned)f2bf(f1[i]) << 16);
                pk.y = (unsigned)f2bf(f2[i]) | ((unsigned)f2bf(f3[i]) << 16);
                *(uint2*)&sxa[pix4 + i][4 * cpack] = pk;
            }
        }
        __syncthreads();
        #pragma unroll
        for (int ks = 0; ks < 64; ks += 32) {
            const bf16x8 a = *(const bf16x8*)&sxa[wave * 16 + l15][ks + quad * 8];
            #pragma unroll
            for (int nt = 0; nt < 8; ++nt) {
                const bf16x8 b = *(const bf16x8*)(wb + (size_t)(nt * 16 + l15) * CIN
                                                     + ck + ks + quad * 8);
                acc[nt] = __builtin_amdgcn_mfma_f32_16x16x32_bf16(a, b, acc[nt], 0, 0, 0);
            }
        }
    }
    // epilogue: D row = quad*4+reg (pix), col = l15 (o). + bias.
    float bb[8];
    #pragma unroll
    for (int nt = 0; nt < 8; ++nt) {
        int o = nt * 16 + l15;
        bb[nt] = (o < NOUT) ? bias[o] : 0.0f;
    }
    float* outp = ws + WS_OUT;
    #pragma unroll
    for (int nt = 0; nt < 8; ++nt) {
        #pragma unroll
        for (int reg = 0; reg < 4; ++reg) {
            int pix = pixbase + wave * 16 + quad * 4 + reg;
            outp[((size_t)bn * HW + pix) * OP + nt * 16 + l15] = acc[nt][reg] + bb[nt];
        }
    }
}

// ---------------- K2b: fused softmax + geometry + group-GEMM, depth-split ----------
#define DQ 15
__global__ __launch_bounds__(256) void k2b_fused(float* __restrict__ ws,
                                                 float* __restrict__ dout) {
    __shared__ float sRow[96][124];            // conv rows -> p (0..58) + feats (59..122)
    __shared__ unsigned short sv16[DQ * 96];   // per-(dlocal,j) voxel id or 0xFFFF
    __shared__ double sT[N_ * TDREC];
    __shared__ int sflag[DQ];
    const int tid = threadIdx.x;
    const int bw = blockIdx.x;
    const int b = bw / FW, w = bw - b * FW;
    const int dbase = blockIdx.y * DQ;
    const int nd = min(DQ, DEPN - dbase);

    // A: stage conv rows + transforms
    {
        const float* outbase = ws + WS_OUT;
        for (int i = tid; i < 96 * 31; i += 256) {
            int r = i / 31, c4 = (i - r * 31) * 4;
            int n = r >> 4, h = r & 15;
            size_t pix = (size_t)(b * N_ + n) * HW + (size_t)h * FW + w;
            *(float4*)&sRow[r][c4] = *(const float4*)(outbase + pix * OP + c4);
        }
        if (tid < N_ * TDREC) sT[tid] = ((const double*)ws)[b * (N_ * TDREC) + tid];
    }
    __syncthreads();

    // B: softmax per row (one wave handles 24 rows)
    {
        const int lane = tid & 63;
        for (int r = (tid >> 6) * 24; r < (tid >> 6) * 24 + 24; ++r) {
            float v = (lane < DEPN) ? sRow[r][lane] : -INFINITY;
            float m = v;
            #pragma unroll
            for (int off = 32; off > 0; off >>= 1) m = fmaxf(m, __shfl_xor(m, off, 64));
            float e = (lane < DEPN) ? expf(v - m) : 0.0f;
            float s = e;
            #pragma unroll
            for (int off = 32; off > 0; off >>= 1) s += __shfl_xor(s, off, 64);
            if (lane < DEPN) sRow[r][lane] = e / s;
        }
    }
    __syncthreads();

    // C: dump this block's p-slab range to ws (coalesced)
    {
        float* ps = ws + WS_PS + (size_t)bw * (DEPN * 96);
        for (int idx = tid; idx < nd * 96; idx += 256) {
            int dl = idx / 96, j = idx - dl * 96;
            ps[(dbase + dl) * 96 + j] = sRow[j][dbase + dl];
        }
    }
    // D: geometry for this d-range. Bit-exact validated f64 chain.
    {
        #pragma clang fp contract(off)
        const double xs = (w == 43) ? 703.0 : (double)w * (703.0 / 43.0);
        const double BXY = (double)(-51.2000007629394531f);  // f32 value of BX-DX/2
        for (int idx = tid; idx < nd * 96; idx += 256) {
            int dl = idx / 96, j = idx - dl * 96;
            int n = j >> 4, h = j & 15;
            const double* T = &sT[n * TDREC];
            const double ys = (double)(h * 17);
            const double u0 = xs - T[9];
            const double u1 = ys - T[10];
            const double u2 = (double)(dbase + dl + 1) - T[11];
            const double p0 = (T[0]*u0 + T[1]*u1) + T[2]*u2;
            const double p1 = (T[3]*u0 + T[4]*u1) + T[5]*u2;
            const double p2 = (T[6]*u0 + T[7]*u1) + T[8]*u2;
            const double q0 = p0 * p2, q1 = p1 * p2, q2 = p2;
            const double r0 = ((T[12]*q0 + T[13]*q1) + T[14]*q2) + T[21];
            const double r1 = ((T[15]*q0 + T[16]*q1) + T[17]*q2) + T[22];
            const double r2 = ((T[18]*q0 + T[19]*q1) + T[20]*q2) + T[23];
            const double g0 = (T[24]*r0 + T[25]*r1) + T[26]*r2;
            const double g1 = (T[27]*r0 + T[28]*r1) + T[29]*r2;
            const double g2 = (T[30]*r0 + T[31]*r1) + T[32]*r2;
            const double fx = floor((g0 - BXY) / 0.8);
            const double fy = floor((g1 - BXY) / 0.8);
            const bool keep = (fx >= 0.0) & (fx < 128.0) & (fy >= 0.0) & (fy < 128.0) &
                              (g2 >= -10.0) & (g2 < 10.0);
            sv16[idx] = keep ? (unsigned short)((int)fx * NX + (int)fy) : (unsigned short)0xFFFF;
        }
    }
    __syncthreads();

    // E: per-d uniformity flags + mask dropped p's to zero
    if (tid < nd) {
        int u = -1; bool mix = false;
        for (int j = 0; j < 96; ++j) {
            int v = sv16[tid * 96 + j];
            if (v != 0xFFFF) { if (u < 0) u = v; else if (v != u) mix = true; }
        }
        sflag[tid] = mix ? -2 : u;
        ((int*)(ws + WS_VOX))[bw * DEPN + dbase + tid] = mix ? -1 : u;
    }
    for (int idx = tid; idx < nd * 96; idx += 256) {
        if (sv16[idx] == 0xFFFF) {
            int dl = idx / 96, j = idx - dl * 96;
            sRow[j][dbase + dl] = 0.0f;
        }
    }
    __syncthreads();

    // F: C[d][c] = sum_j p[j][d] * f[j][c]; thread = (d_local, 4 channels)
    const int di = tid >> 4, ci = tid & 15;
    if (di < nd) {
        float a0 = 0.f, a1 = 0.f, a2 = 0.f, a3 = 0.f;
        const int dcol = dbase + di;
        for (int j = 0; j < 96; ++j) {
            const float p = sRow[j][dcol];
            const float4 f4 = *(const float4*)&sRow[j][DEPN + 4 * ci];
            a0 = fmaf(p, f4.x, a0); a1 = fmaf(p, f4.y, a1);
            a2 = fmaf(p, f4.z, a2); a3 = fmaf(p, f4.w, a3);
        }
        float* cg = ws + WS_C + (size_t)bw * (DEPN * 64);
        float4 st = { a0, a1, a2, a3 };
        *(float4*)&cg[dcol * 64 + 4 * ci] = st;
    }
    // G: rare per-point slow path for mixed groups
    for (int dl = 0; dl < nd; ++dl) {
        if (sflag[dl] == -2) {
            int c = tid & 63, g = tid >> 6;
            for (int jj = 0; jj < 24; ++jj) {
                int j = g * 24 + jj;
                int v = sv16[dl * 96 + j];
                if (v != 0xFFFF)
                    atomicAdd(dout + (((size_t)(b * CT + c)) << 14) + v,
                              sRow[j][dbase + dl] * sRow[j][DEPN + c]);
            }
        }
    }
}

// ---------------- K2c: per-(b,d) voxel reduction + depth output ----------------
__global__ __launch_bounds__(256) void k2c_reduce(const float* __restrict__ ws,
                                                  float* __restrict__ dout) {
    __shared__ float acc[FW][64];
    __shared__ int tags[FW];
    __shared__ unsigned char slot[FW];
    __shared__ int wvox[FW];
    __shared__ int nsh;
    const int d = blockIdx.x, b = blockIdx.y;
    const int tid = threadIdx.x;
    if (tid < FW) wvox[tid] = ((const int*)(ws + WS_VOX))[(b * FW + tid) * DEPN + d];
    for (int i = tid; i < FW * 64; i += 256) (&acc[0][0])[i] = 0.0f;
    __syncthreads();
    if (tid < 64) {  // wave 0: dedup voxel ids into slots
        const int lane = tid;
        int v = (lane < FW) ? wvox[lane] : -1;
        int firstw = lane;
        for (int w2 = 0; w2 < FW; ++w2) {
            int vw = __shfl(v, w2, 64);
            if (v >= 0 && vw == v && w2 < firstw) firstw = w2;
        }
        unsigned long long leaders = __ballot(v >= 0 && firstw == lane);
        if (lane < FW) {
            if (v >= 0) {
                int s = __popcll(leaders & ((1ull << firstw) - 1ull));
                slot[lane] = (unsigned char)s;
                if (firstw == lane) tags[s] = v;
            } else slot[lane] = 255;
        }
        if (lane == 0) nsh = __popcll(leaders);
    }
    __syncthreads();
    const int c = tid & 63, g = tid >> 6;
    for (int w = g; w < FW; w += 4) {
        if (wvox[w] >= 0) {
            float v = ws[WS_C + ((size_t)(b * FW + w) * DEPN + d) * 64 + c];
            atomicAdd(&acc[slot[w]][c], v);
        }
    }
    __syncthreads();
    const int ns = nsh;
    for (int s = g; s < ns; s += 4)
        atomicAdd(dout + (((size_t)(b * CT + c)) << 14) + tags[s], acc[s][c]);
    // depth output for this (b,d): all n, coalesced writes
    for (int i = tid; i < N_ * HW; i += 256) {
        int n = i / HW, t2 = i - n * HW;
        int h = t2 / FW, w2 = t2 - h * FW;
        float p = ws[WS_PS + ((size_t)(b * FW + w2) * DEPN + d) * 96 + n * FH + h];
        dout[DEPTH_OFF + ((size_t)(b * N_ + n) * DEPN + d) * HW + t2] = p;
    }
}

// ---------------- launcher ----------------
extern "C" void kernel_launch(void* const* d_in, const int* in_sizes, int n_in,
                              void* d_out, int out_size, void* d_ws, size_t ws_size,
                              hipStream_t stream) {
    const float* x      = (const float*)d_in[0];
    const float* rots   = (const float*)d_in[1];
    const float* trans  = (const float*)d_in[2];
    const float* intr   = (const float*)d_in[3];
    const float* prots  = (const float*)d_in[4];
    const float* ptrans = (const float*)d_in[5];
    const float* bda    = (const float*)d_in[6];
    const float* W      = (const float*)d_in[7];
    const float* bias   = (const float*)d_in[8];
    float* out = (float*)d_out;
    float* ws  = (float*)d_ws;

    hipMemsetAsync(d_out, 0, (size_t)BEV_ELEMS * sizeof(float), stream);
    k0_prep<<<128, 256, 0, stream>>>(rots, trans, intr, prots, ptrans, bda, W, ws);
    k1_gemm<<<dim3(HW / 64, B_ * N_), 256, 0, stream>>>(x, bias, ws);
    k2b_fused<<<dim3(B_ * FW, 4), 256, 0, stream>>>(ws, out);
    k2c_reduce<<<dim3(DEPN, B_), 256, 0, stream>>>(ws, out);
}

// Round 9
// 191.548 us; speedup vs baseline: 1.1583x; 1.0557x over previous
//
#include <hip/hip_runtime.h>
#include <math.h>

// ---------------- problem constants ----------------
#define CIN   512
#define NOUT  123      // DEPTH + CT
#define DEPN  59
#define CT    64
#define B_    4
#define N_    6
#define FH    16
#define FW    44
#define HW    704      // FH*FW
#define NPIX  (B_*N_*HW)          // 16896
#define NX    128
#define BEV_ELEMS (B_*CT*NX*NX)   // 4,194,304
#define DEPTH_OFF BEV_ELEMS

// ws layout (float offsets). Double region first (8B aligned at base).
#define TDREC   40
#define WS_WB   1920                       // bf16 weight [128 o][512 c]
#define WS_PS   (WS_WB + 32768)            // p-slab  [row = bw*96 + n*16+h][64] (cols 0..58)
#define WS_FS   (WS_PS + NPIX*64)          // f-slab  [row][64]
#define WS_C    (WS_FS + NPIX*64)          // group sums [bw][59][64]
#define WS_VOX  (WS_C + B_*FW*DEPN*64)     // int [bw][59]

typedef short bf16x8 __attribute__((ext_vector_type(8)));
typedef float f32x4  __attribute__((ext_vector_type(4)));

__device__ inline unsigned short f2bf(float f) {   // RNE f32->bf16
    unsigned u = __float_as_uint(f);
    return (unsigned short)((u + 0x7fffu + ((u >> 16) & 1u)) >> 16);
}

// ---------------- K0: bf16 weight build + per-(b,n) f64 transforms ----------------
__device__ inline void inv3d(const double* m, double* o) {
    #pragma clang fp contract(off)
    double c00 = m[4]*m[8] - m[5]*m[7];
    double c01 = m[5]*m[6] - m[3]*m[8];
    double c02 = m[3]*m[7] - m[4]*m[6];
    double det = m[0]*c00 + m[1]*c01 + m[2]*c02;
    o[0] = c00/det; o[1] = (m[2]*m[7]-m[1]*m[8])/det; o[2] = (m[1]*m[5]-m[2]*m[4])/det;
    o[3] = c01/det; o[4] = (m[0]*m[8]-m[2]*m[6])/det; o[5] = (m[2]*m[3]-m[0]*m[5])/det;
    o[6] = c02/det; o[7] = (m[1]*m[6]-m[0]*m[7])/det; o[8] = (m[0]*m[4]-m[1]*m[3])/det;
}
__device__ inline void mm3d(const double* a, const double* b, double* o) {
    #pragma clang fp contract(off)
    for (int i = 0; i < 3; ++i)
        for (int k = 0; k < 3; ++k)
            o[i*3+k] = (a[i*3+0]*b[0*3+k] + a[i*3+1]*b[1*3+k]) + a[i*3+2]*b[2*3+k];
}

__global__ void k0_prep(const float* __restrict__ rots, const float* __restrict__ trans,
                        const float* __restrict__ intr, const float* __restrict__ prots,
                        const float* __restrict__ ptrans, const float* __restrict__ bda,
                        const float* __restrict__ W, float* __restrict__ ws) {
    int tid = blockIdx.x * 256 + threadIdx.x;
    int stride = gridDim.x * 256;
    unsigned short* wb = (unsigned short*)(ws + WS_WB);
    for (int i = tid; i < 128 * CIN; i += stride) {
        int o = i >> 9, c = i & 511;
        wb[i] = (o < NOUT) ? f2bf(W[o * CIN + c]) : (unsigned short)0;
    }
    if (blockIdx.x == 0 && threadIdx.x < B_ * N_) {
        #pragma clang fp contract(off)
        int t = threadIdx.x;
        int b = t / N_;
        double* X = (double*)(ws) + t * TDREC;
        double PR[9], Kd[9], Rd[9], Bd[9];
        for (int i = 0; i < 9; ++i) PR[i] = (double)prots[t * 9 + i];
        for (int i = 0; i < 9; ++i) Kd[i] = (double)intr[t * 9 + i];
        for (int i = 0; i < 9; ++i) Rd[i] = (double)rots[t * 9 + i];
        for (int i = 0; i < 9; ++i) Bd[i] = (double)bda[b * 9 + i];
        double iPR[9]; inv3d(PR, iPR);
        for (int i = 0; i < 9; ++i) X[i] = iPR[i];
        for (int i = 0; i < 3; ++i) X[9 + i] = (double)ptrans[t * 3 + i];
        double iK[9];  inv3d(Kd, iK);
        double comb[9]; mm3d(Rd, iK, comb);
        for (int i = 0; i < 9; ++i) X[12 + i] = comb[i];
        for (int i = 0; i < 3; ++i) X[21 + i] = (double)trans[t * 3 + i];
        for (int i = 0; i < 9; ++i) X[24 + i] = Bd[i];
    }
}

// ---------------- K1: bf16 MFMA GEMM + fused softmax epilogue ----------------
// Block: 64 pix x 128 o, 4 waves. Epilogue: per-pixel-row softmax over depth
// cols (cross-lane in D-layout: row spread over 16 lanes x 4 nt tiles),
// writes p-slab (cols 0..58) and f-slab (cols 59..122 -> 0..63) directly.
__global__ __launch_bounds__(256) void k1_gemm(const float* __restrict__ x,
                                               const float* __restrict__ bias,
                                               float* __restrict__ ws) {
    __shared__ unsigned short sxa[64][72];   // A tile bf16 [pix][c]
    const int tid = threadIdx.x;
    const int wave = tid >> 6, lane = tid & 63;
    const int l15 = lane & 15, quad = lane >> 4;
    const int bn = blockIdx.y;
    const int pixbase = blockIdx.x * 64;
    const float* xg = x + (size_t)bn * CIN * HW + pixbase;
    const unsigned short* wb = (const unsigned short*)(ws + WS_WB);
    const int cpack = tid >> 4;
    const int pix4 = (tid & 15) * 4;

    f32x4 acc[8] = {};
    for (int ck = 0; ck < CIN; ck += 64) {
        __syncthreads();
        {   // stage 64c x 64pix, transpose+convert
            const float* src = xg + (size_t)(ck + 4 * cpack) * HW + pix4;
            const float4 r0 = *(const float4*)(src);
            const float4 r1 = *(const float4*)(src + HW);
            const float4 r2 = *(const float4*)(src + 2 * HW);
            const float4 r3 = *(const float4*)(src + 3 * HW);
            const float* f0 = (const float*)&r0; const float* f1 = (const float*)&r1;
            const float* f2 = (const float*)&r2; const float* f3 = (const float*)&r3;
            #pragma unroll
            for (int i = 0; i < 4; ++i) {
                uint2 pk;
                pk.x = (unsigned)f2bf(f0[i]) | ((unsigned)f2bf(f1[i]) << 16);
                pk.y = (unsigned)f2bf(f2[i]) | ((unsigned)f2bf(f3[i]) << 16);
                *(uint2*)&sxa[pix4 + i][4 * cpack] = pk;
            }
        }
        __syncthreads();
        #pragma unroll
        for (int ks = 0; ks < 64; ks += 32) {
            const bf16x8 a = *(const bf16x8*)&sxa[wave * 16 + l15][ks + quad * 8];
            #pragma unroll
            for (int nt = 0; nt < 8; ++nt) {
                const bf16x8 b = *(const bf16x8*)(wb + (size_t)(nt * 16 + l15) * CIN
                                                     + ck + ks + quad * 8);
                acc[nt] = __builtin_amdgcn_mfma_f32_16x16x32_bf16(a, b, acc[nt], 0, 0, 0);
            }
        }
    }
    // epilogue: softmax + split store. D row = quad*4+reg (pix), col = l15 (o).
    const int b = bn / N_, n = bn - b * N_;
    float bb[8];
    #pragma unroll
    for (int nt = 0; nt < 8; ++nt) {
        int o = nt * 16 + l15;
        bb[nt] = (o < NOUT) ? bias[o] : 0.0f;
    }
    float* ps = ws + WS_PS;
    float* fs = ws + WS_FS;
    #pragma unroll
    for (int reg = 0; reg < 4; ++reg) {
        int pix = pixbase + wave * 16 + quad * 4 + reg;
        int h = pix / FW, w = pix - h * FW;
        size_t row = (size_t)(b * FW + w) * 96 + n * FH + h;
        float v[4]; float m = -INFINITY;
        #pragma unroll
        for (int nt = 0; nt < 4; ++nt) {
            v[nt] = acc[nt][reg] + bb[nt];
            if (nt * 16 + l15 < DEPN) m = fmaxf(m, v[nt]);
        }
        #pragma unroll
        for (int msk = 8; msk >= 1; msk >>= 1) m = fmaxf(m, __shfl_xor(m, msk, 64));
        float e[4], s = 0.0f;
        #pragma unroll
        for (int nt = 0; nt < 4; ++nt) {
            e[nt] = (nt * 16 + l15 < DEPN) ? expf(v[nt] - m) : 0.0f;
            s += e[nt];
        }
        #pragma unroll
        for (int msk = 8; msk >= 1; msk >>= 1) s += __shfl_xor(s, msk, 64);
        const float inv = 1.0f / s;
        #pragma unroll
        for (int nt = 0; nt < 4; ++nt) {
            int o = nt * 16 + l15;
            if (o < DEPN) ps[row * 64 + o] = e[nt] * inv;
            else fs[row * 64 + (o - DEPN)] = v[nt];      // o in 59..63 (nt==3 tail)
        }
        #pragma unroll
        for (int nt = 4; nt < 8; ++nt) {
            int o = nt * 16 + l15;
            if (o < NOUT) fs[row * 64 + (o - DEPN)] = acc[nt][reg] + bb[nt];
        }
    }
}

// ---------------- K2b: geometry + group-GEMM (16-depth chunks) ----------------
#define DQ2 16
__global__ __launch_bounds__(256) void k2b_geom(float* __restrict__ ws,
                                                float* __restrict__ dout) {
    __shared__ float sF[96][64];               // feats
    __shared__ float sP[DQ2][97];              // p tile, transposed, padded
    __shared__ unsigned short sv16[DQ2 * 96];  // voxel id or 0xFFFF
    __shared__ double sT[N_ * TDREC];
    __shared__ int sflag[DQ2];
    const int tid = threadIdx.x;
    const int bw = blockIdx.x;
    const int b = bw / FW, w = bw - b * FW;
    const int dbase = blockIdx.y * DQ2;
    const int nd = min(DQ2, DEPN - dbase);

    {   // stage F + P(transposed) + transforms
        const float* fsrc = ws + WS_FS + (size_t)bw * (96 * 64);
        const float* psrc = ws + WS_PS + (size_t)bw * (96 * 64);
        for (int i = tid; i < 96 * 16; i += 256) {
            int j = i >> 4, c4 = (i & 15) * 4;
            *(float4*)&sF[j][c4] = *(const float4*)(fsrc + j * 64 + c4);
        }
        for (int i = tid; i < 96 * 16; i += 256) {
            int j = i >> 4, t = i & 15;
            sP[t][j] = psrc[j * 64 + dbase + t];
        }
        if (tid < N_ * TDREC) sT[tid] = ((const double*)ws)[b * (N_ * TDREC) + tid];
    }
    __syncthreads();

    {   // geometry: bit-exact validated f64 chain (R1-R5 ulp analysis)
        #pragma clang fp contract(off)
        const double xs = (w == 43) ? 703.0 : (double)w * (703.0 / 43.0);
        const double BXY = (double)(-51.2000007629394531f);  // f32 value of BX-DX/2
        for (int idx = tid; idx < nd * 96; idx += 256) {
            int dl = idx / 96, j = idx - dl * 96;
            int n = j >> 4, h = j & 15;
            const double* T = &sT[n * TDREC];
            const double ys = (double)(h * 17);
            const double u0 = xs - T[9];
            const double u1 = ys - T[10];
            const double u2 = (double)(dbase + dl + 1) - T[11];
            const double p0 = (T[0]*u0 + T[1]*u1) + T[2]*u2;
            const double p1 = (T[3]*u0 + T[4]*u1) + T[5]*u2;
            const double p2 = (T[6]*u0 + T[7]*u1) + T[8]*u2;
            const double q0 = p0 * p2, q1 = p1 * p2, q2 = p2;
            const double r0 = ((T[12]*q0 + T[13]*q1) + T[14]*q2) + T[21];
            const double r1 = ((T[15]*q0 + T[16]*q1) + T[17]*q2) + T[22];
            const double r2 = ((T[18]*q0 + T[19]*q1) + T[20]*q2) + T[23];
            const double g0 = (T[24]*r0 + T[25]*r1) + T[26]*r2;
            const double g1 = (T[27]*r0 + T[28]*r1) + T[29]*r2;
            const double g2 = (T[30]*r0 + T[31]*r1) + T[32]*r2;
            const double fx = floor((g0 - BXY) / 0.8);
            const double fy = floor((g1 - BXY) / 0.8);
            const bool keep = (fx >= 0.0) & (fx < 128.0) & (fy >= 0.0) & (fy < 128.0) &
                              (g2 >= -10.0) & (g2 < 10.0);
            sv16[idx] = keep ? (unsigned short)((int)fx * NX + (int)fy) : (unsigned short)0xFFFF;
        }
    }
    __syncthreads();

    // flags + mask dropped p's
    if (tid < nd) {
        int u = -1; bool mix = false;
        for (int j = 0; j < 96; ++j) {
            int v = sv16[tid * 96 + j];
            if (v != 0xFFFF) { if (u < 0) u = v; else if (v != u) mix = true; }
        }
        sflag[tid] = mix ? -2 : u;
        ((int*)(ws + WS_VOX))[bw * DEPN + dbase + tid] = mix ? -1 : u;
    }
    for (int idx = tid; idx < nd * 96; idx += 256) {
        if (sv16[idx] == 0xFFFF) {
            int dl = idx / 96, j = idx - dl * 96;
            sP[dl][j] = 0.0f;
        }
    }
    __syncthreads();

    // GEMM: C[d][c] = sum_j p[dl][j] * f[j][c]; thread = (dl, 4 channels)
    const int dl = tid >> 4, ci = tid & 15;
    if (dl < nd) {
        float a0 = 0.f, a1 = 0.f, a2 = 0.f, a3 = 0.f;
        for (int j = 0; j < 96; ++j) {
            const float p = sP[dl][j];
            const float4 f4 = *(const float4*)&sF[j][4 * ci];
            a0 = fmaf(p, f4.x, a0); a1 = fmaf(p, f4.y, a1);
            a2 = fmaf(p, f4.z, a2); a3 = fmaf(p, f4.w, a3);
        }
        float* cg = ws + WS_C + (size_t)bw * (DEPN * 64);
        float4 st = { a0, a1, a2, a3 };
        *(float4*)&cg[(dbase + dl) * 64 + 4 * ci] = st;
    }
    // rare per-point slow path for mixed groups
    for (int d2 = 0; d2 < nd; ++d2) {
        if (sflag[d2] == -2) {
            int c = tid & 63, g = tid >> 6;
            for (int jj = 0; jj < 24; ++jj) {
                int j = g * 24 + jj;
                int v = sv16[d2 * 96 + j];
                if (v != 0xFFFF)
                    atomicAdd(dout + (((size_t)(b * CT + c)) << 14) + v,
                              sP[d2][j] * sF[j][c]);
            }
        }
    }
}

// ---------------- K2c: per-(b,d) voxel reduction + depth output ----------------
__global__ __launch_bounds__(256) void k2c_reduce(const float* __restrict__ ws,
                                                  float* __restrict__ dout) {
    __shared__ float acc[FW][64];
    __shared__ int tags[FW];
    __shared__ unsigned char slot[FW];
    __shared__ int wvox[FW];
    __shared__ int nsh;
    const int d = blockIdx.x, b = blockIdx.y;
    const int tid = threadIdx.x;
    if (tid < FW) wvox[tid] = ((const int*)(ws + WS_VOX))[(b * FW + tid) * DEPN + d];
    for (int i = tid; i < FW * 64; i += 256) (&acc[0][0])[i] = 0.0f;
    __syncthreads();
    if (tid < 64) {  // wave 0: dedup voxel ids into slots
        const int lane = tid;
        int v = (lane < FW) ? wvox[lane] : -1;
        int firstw = lane;
        for (int w2 = 0; w2 < FW; ++w2) {
            int vw = __shfl(v, w2, 64);
            if (v >= 0 && vw == v && w2 < firstw) firstw = w2;
        }
        unsigned long long leaders = __ballot(v >= 0 && firstw == lane);
        if (lane < FW) {
            if (v >= 0) {
                int s = __popcll(leaders & ((1ull << firstw) - 1ull));
                slot[lane] = (unsigned char)s;
                if (firstw == lane) tags[s] = v;
            } else slot[lane] = 255;
        }
        if (lane == 0) nsh = __popcll(leaders);
    }
    __syncthreads();
    const int c = tid & 63, g = tid >> 6;
    for (int w = g; w < FW; w += 4) {
        if (wvox[w] >= 0) {
            float v = ws[WS_C + ((size_t)(b * FW + w) * DEPN + d) * 64 + c];
            atomicAdd(&acc[slot[w]][c], v);
        }
    }
    __syncthreads();
    const int ns = nsh;
    for (int s = g; s < ns; s += 4)
        atomicAdd(dout + (((size_t)(b * CT + c)) << 14) + tags[s], acc[s][c]);
    // depth output for this (b,d): all n, coalesced writes (reads p-slab via L2)
    for (int i = tid; i < N_ * HW; i += 256) {
        int n = i / HW, t2 = i - n * HW;
        int h = t2 / FW, w2 = t2 - h * FW;
        float p = ws[WS_PS + ((size_t)(b * FW + w2) * 96 + n * FH + h) * 64 + d];
        dout[DEPTH_OFF + ((size_t)(b * N_ + n) * DEPN + d) * HW + t2] = p;
    }
}

// ---------------- launcher ----------------
extern "C" void kernel_launch(void* const* d_in, const int* in_sizes, int n_in,
                              void* d_out, int out_size, void* d_ws, size_t ws_size,
                              hipStream_t stream) {
    const float* x      = (const float*)d_in[0];
    const float* rots   = (const float*)d_in[1];
    const float* trans  = (const float*)d_in[2];
    const float* intr   = (const float*)d_in[3];
    const float* prots  = (const float*)d_in[4];
    const float* ptrans = (const float*)d_in[5];
    const float* bda    = (const float*)d_in[6];
    const float* W      = (const float*)d_in[7];
    const float* bias   = (const float*)d_in[8];
    float* out = (float*)d_out;
    float* ws  = (float*)d_ws;

    hipMemsetAsync(d_out, 0, (size_t)BEV_ELEMS * sizeof(float), stream);
    k0_prep<<<128, 256, 0, stream>>>(rots, trans, intr, prots, ptrans, bda, W, ws);
    k1_gemm<<<dim3(HW / 64, B_ * N_), 256, 0, stream>>>(x, bias, ws);
    k2b_geom<<<dim3(B_ * FW, 4), 256, 0, stream>>>(ws, out);
    k2c_reduce<<<dim3(DEPN, B_), 256, 0, stream>>>(ws, out);
}